// Round 1
// baseline (1005.225 us; speedup 1.0000x reference)
//
#include <hip/hip_runtime.h>
#include <math.h>

#define NN 100000
#define NE 3200000
#define NG 1024
#define FDIM 128
#define NFC1 64
#define NFC2 10

#define BSHIFT 9
#define NBUCK 196   // ceil(NN/512)
#define CAP 20480   // mean 16384, sigma ~127 -> 32-sigma headroom
#define EPB 16      // edges per thread in bin_kernel

// ---------------- pass 1: bin edges into 196 coarse buckets ----------------
// Packed value: (dst & 511) << 17 | src   (src < 2^17, dst_local < 2^9)
__global__ __launch_bounds__(256) void bin_kernel(const int* __restrict__ src,
                                                  const int* __restrict__ dst,
                                                  int* __restrict__ gcursor,
                                                  int* __restrict__ staging) {
  __shared__ int hist[NBUCK];
  __shared__ int base[NBUCK];
  int t = threadIdx.x;
  for (int i = t; i < NBUCK; i += 256) hist[i] = 0;
  __syncthreads();
  size_t e0 = (size_t)blockIdx.x * (256 * EPB);
  int bk[EPB], rank[EPB], val[EPB];
#pragma unroll
  for (int j = 0; j < EPB; ++j) {
    size_t e = e0 + (size_t)j * 256 + t;
    if (e < NE) {
      int d = dst[e];
      int s = src[e];
      bk[j] = d >> BSHIFT;
      val[j] = ((d & 511) << 17) | s;
      rank[j] = atomicAdd(&hist[bk[j]], 1);
    } else {
      bk[j] = -1;
    }
  }
  __syncthreads();
  for (int i = t; i < NBUCK; i += 256) base[i] = atomicAdd(&gcursor[i], hist[i]);
  __syncthreads();
#pragma unroll
  for (int j = 0; j < EPB; ++j) {
    if (bk[j] >= 0) {
      int pos = base[bk[j]] + rank[j];
      if (pos < CAP) staging[(size_t)bk[j] * CAP + pos] = val[j];
    }
  }
}

// ---------------- pass 2: per-bucket CSR finalize (scan fused in) ----------------
__global__ __launch_bounds__(256) void build_kernel(const int* __restrict__ staging,
                                                    const int* __restrict__ gcursor,
                                                    int* __restrict__ row_off,
                                                    int* __restrict__ esrc) {
  __shared__ int ncnt[512];
  __shared__ int noff[513];
  __shared__ int part[256];
  __shared__ int sscan[256];
  int b = blockIdx.x, t = threadIdx.x;
  // inline exclusive scan of bucket counts to get this block's edge base
  int gv = (t < NBUCK) ? gcursor[t] : 0;
  sscan[t] = gv;
  __syncthreads();
  for (int st = 1; st < 256; st <<= 1) {
    int u = (t >= st) ? sscan[t - st] : 0;
    __syncthreads();
    sscan[t] += u;
    __syncthreads();
  }
  int cnt = gcursor[b];
  int ebase = sscan[b] - cnt;  // exclusive prefix
  int nbase = b << BSHIFT;
  ncnt[t] = 0;
  ncnt[t + 256] = 0;
  __syncthreads();
  const int* sp = staging + (size_t)b * CAP;
  for (int i = t; i < cnt; i += 256) {
    int dl = sp[i] >> 17;
    atomicAdd(&ncnt[dl], 1);
  }
  __syncthreads();
  int a0 = ncnt[2 * t], a1 = ncnt[2 * t + 1];
  part[t] = a0 + a1;
  __syncthreads();
  for (int st = 1; st < 256; st <<= 1) {
    int u = (t >= st) ? part[t - st] : 0;
    __syncthreads();
    part[t] += u;
    __syncthreads();
  }
  int excl = (t > 0) ? part[t - 1] : 0;
  noff[2 * t] = excl;
  noff[2 * t + 1] = excl + a0;
  if (t == 255) noff[512] = part[255];
  __syncthreads();
  for (int i = t; i <= 512; i += 256) {
    int n = nbase + i;
    if (n <= NN) row_off[n] = ebase + noff[i];
  }
  // reuse ncnt as write cursors
  ncnt[2 * t] = noff[2 * t];
  ncnt[2 * t + 1] = noff[2 * t + 1];
  __syncthreads();
  for (int i = t; i < cnt; i += 256) {
    int v = sp[i];
    int dl = v >> 17;
    int pos = atomicAdd(&ncnt[dl], 1);
    esrc[ebase + pos] = v & 0x1FFFF;
  }
}

// ---------------- fused conv layer: out = relu(gather(xin)@W + bias) ----------------
// 512 threads = 8 waves; 64 dst nodes per block.
// Phase 1 (CHANGED this round): paired-edge dwordx4 gather. Lanes 0-31 read the
//   512B row of edge e as 32 x float4; lanes 32-63 read edge e+1. Main loop does
//   16 edges/iter with 8 dwordx4 in flight (128 B/lane in flight, 2x the old
//   float2 scheme; VMEM instruction count halved). Cross-half combine is 4
//   __shfl_xor(.,32) per node. Transposed LDS write pattern unchanged.
// Phase 2: wave w GEMMs its own 8 rows x 128 cols from aT (stride 68, b128
//   broadcast reads) with W streamed from L1; relu+bias; float4 store.
__global__ __launch_bounds__(512) void conv_fused(const float4* __restrict__ xin,
                                                  const int* __restrict__ row_off,
                                                  const int* __restrict__ esrc,
                                                  const float* __restrict__ W,
                                                  const float* __restrict__ bias,
                                                  float* __restrict__ out) {
  __shared__ __align__(16) float aT[128 * 68];
  int t = threadIdx.x;
  int w = t >> 6;
  int lane = t & 63;
  int half = lane >> 5;   // which edge of the pair this lane reads
  int c4 = lane & 31;     // which float4 of the 512B row
  int nodebase = blockIdx.x * 64;

  // ---- phase 1: gather-aggregate 8 nodes for this wave ----
  for (int i = 0; i < 8; ++i) {
    int r = w * 8 + i;
    int node = nodebase + r;
    int beg = 0, end = 0;
    if (node < NN) {
      beg = __builtin_amdgcn_readfirstlane(row_off[node]);
      end = __builtin_amdgcn_readfirstlane(row_off[node + 1]);
    }
    float4 acc = make_float4(0.f, 0.f, 0.f, 0.f);
    int e = beg;
    // main: 16 edges / iter, 8 x dwordx4 in flight
    for (; e + 16 <= end; e += 16) {
      int i0 = __builtin_amdgcn_readfirstlane(esrc[e + 0]);
      int i1 = __builtin_amdgcn_readfirstlane(esrc[e + 1]);
      int i2 = __builtin_amdgcn_readfirstlane(esrc[e + 2]);
      int i3 = __builtin_amdgcn_readfirstlane(esrc[e + 3]);
      int i4 = __builtin_amdgcn_readfirstlane(esrc[e + 4]);
      int i5 = __builtin_amdgcn_readfirstlane(esrc[e + 5]);
      int i6 = __builtin_amdgcn_readfirstlane(esrc[e + 6]);
      int i7 = __builtin_amdgcn_readfirstlane(esrc[e + 7]);
      int i8 = __builtin_amdgcn_readfirstlane(esrc[e + 8]);
      int i9 = __builtin_amdgcn_readfirstlane(esrc[e + 9]);
      int i10 = __builtin_amdgcn_readfirstlane(esrc[e + 10]);
      int i11 = __builtin_amdgcn_readfirstlane(esrc[e + 11]);
      int i12 = __builtin_amdgcn_readfirstlane(esrc[e + 12]);
      int i13 = __builtin_amdgcn_readfirstlane(esrc[e + 13]);
      int i14 = __builtin_amdgcn_readfirstlane(esrc[e + 14]);
      int i15 = __builtin_amdgcn_readfirstlane(esrc[e + 15]);
      float4 v0 = xin[(size_t)(half ? i1 : i0) * 32 + c4];
      float4 v1 = xin[(size_t)(half ? i3 : i2) * 32 + c4];
      float4 v2 = xin[(size_t)(half ? i5 : i4) * 32 + c4];
      float4 v3 = xin[(size_t)(half ? i7 : i6) * 32 + c4];
      float4 v4 = xin[(size_t)(half ? i9 : i8) * 32 + c4];
      float4 v5 = xin[(size_t)(half ? i11 : i10) * 32 + c4];
      float4 v6 = xin[(size_t)(half ? i13 : i12) * 32 + c4];
      float4 v7 = xin[(size_t)(half ? i15 : i14) * 32 + c4];
      acc.x += ((v0.x + v1.x) + (v2.x + v3.x)) + ((v4.x + v5.x) + (v6.x + v7.x));
      acc.y += ((v0.y + v1.y) + (v2.y + v3.y)) + ((v4.y + v5.y) + (v6.y + v7.y));
      acc.z += ((v0.z + v1.z) + (v2.z + v3.z)) + ((v4.z + v5.z) + (v6.z + v7.z));
      acc.w += ((v0.w + v1.w) + (v2.w + v3.w)) + ((v4.w + v5.w) + (v6.w + v7.w));
    }
    // mid tail: 8 edges / iter, 4 x dwordx4 in flight
    for (; e + 8 <= end; e += 8) {
      int i0 = __builtin_amdgcn_readfirstlane(esrc[e + 0]);
      int i1 = __builtin_amdgcn_readfirstlane(esrc[e + 1]);
      int i2 = __builtin_amdgcn_readfirstlane(esrc[e + 2]);
      int i3 = __builtin_amdgcn_readfirstlane(esrc[e + 3]);
      int i4 = __builtin_amdgcn_readfirstlane(esrc[e + 4]);
      int i5 = __builtin_amdgcn_readfirstlane(esrc[e + 5]);
      int i6 = __builtin_amdgcn_readfirstlane(esrc[e + 6]);
      int i7 = __builtin_amdgcn_readfirstlane(esrc[e + 7]);
      float4 v0 = xin[(size_t)(half ? i1 : i0) * 32 + c4];
      float4 v1 = xin[(size_t)(half ? i3 : i2) * 32 + c4];
      float4 v2 = xin[(size_t)(half ? i5 : i4) * 32 + c4];
      float4 v3 = xin[(size_t)(half ? i7 : i6) * 32 + c4];
      acc.x += (v0.x + v1.x) + (v2.x + v3.x);
      acc.y += (v0.y + v1.y) + (v2.y + v3.y);
      acc.z += (v0.z + v1.z) + (v2.z + v3.z);
      acc.w += (v0.w + v1.w) + (v2.w + v3.w);
    }
    // pair tail: 2 edges / iter
    for (; e + 2 <= end; e += 2) {
      int i0 = __builtin_amdgcn_readfirstlane(esrc[e + 0]);
      int i1 = __builtin_amdgcn_readfirstlane(esrc[e + 1]);
      float4 v = xin[(size_t)(half ? i1 : i0) * 32 + c4];
      acc.x += v.x;
      acc.y += v.y;
      acc.z += v.z;
      acc.w += v.w;
    }
    // odd tail: 1 edge, lower half only
    if (e < end) {
      int i0 = __builtin_amdgcn_readfirstlane(esrc[e]);
      if (half == 0) {
        float4 v = xin[(size_t)i0 * 32 + c4];
        acc.x += v.x;
        acc.y += v.y;
        acc.z += v.z;
        acc.w += v.w;
      }
    }
    // combine the two edge-halves: both halves end with the full row sum
    acc.x += __shfl_xor(acc.x, 32);
    acc.y += __shfl_xor(acc.y, 32);
    acc.z += __shfl_xor(acc.z, 32);
    acc.w += __shfl_xor(acc.w, 32);
    // transposed store (cols 4*c4..4*c4+3 of row r), split across halves
    if (half == 0) {
      aT[(4 * c4 + 0) * 68 + r] = acc.x;
      aT[(4 * c4 + 1) * 68 + r] = acc.y;
    } else {
      aT[(4 * c4 + 2) * 68 + r] = acc.z;
      aT[(4 * c4 + 3) * 68 + r] = acc.w;
    }
  }
  __syncthreads();

  // ---- phase 2: GEMM 64x128 tile ----
  int rg = lane >> 5;       // 0..1
  int c = lane & 31;        // cols 4c..4c+3
  int rbase = w * 8 + rg * 4;

  float acc[4][4];
#pragma unroll
  for (int r = 0; r < 4; ++r)
#pragma unroll
    for (int j = 0; j < 4; ++j) acc[r][j] = 0.f;

#pragma unroll 4
  for (int k = 0; k < 128; ++k) {
    float4 bv = *(const float4*)(W + k * FDIM + c * 4);
    float4 a0 = *(const float4*)(&aT[k * 68 + rbase]);
    float ar[4] = {a0.x, a0.y, a0.z, a0.w};
#pragma unroll
    for (int r = 0; r < 4; ++r) {
      acc[r][0] += ar[r] * bv.x;
      acc[r][1] += ar[r] * bv.y;
      acc[r][2] += ar[r] * bv.z;
      acc[r][3] += ar[r] * bv.w;
    }
  }

  float4 b4 = *(const float4*)(bias + c * 4);
#pragma unroll
  for (int r = 0; r < 4; ++r) {
    int row = nodebase + rbase + r;
    if (row < NN) {
      float4 o;
      o.x = fmaxf(acc[r][0] + b4.x, 0.f);
      o.y = fmaxf(acc[r][1] + b4.y, 0.f);
      o.z = fmaxf(acc[r][2] + b4.z, 0.f);
      o.w = fmaxf(acc[r][3] + b4.w, 0.f);
      *(float4*)(out + (size_t)row * FDIM + c * 4) = o;
    }
  }
}

// ---------------- fused global pool + FC1 + FC2 + softmax ----------------
__device__ int lower_bound_dev(const int* __restrict__ arr, int n, int val) {
  int lo = 0, hi = n;
  while (lo < hi) {
    int mid = (lo + hi) >> 1;
    if (arr[mid] < val) lo = mid + 1; else hi = mid;
  }
  return lo;
}

__global__ __launch_bounds__(128) void pool_head(const float* __restrict__ x,
                                                 const int* __restrict__ batching,
                                                 const float* __restrict__ Wf1,
                                                 const float* __restrict__ bf1,
                                                 const float* __restrict__ Wf2,
                                                 const float* __restrict__ bf2,
                                                 float* __restrict__ out) {
  __shared__ int se, ee;
  __shared__ float gl[128];
  __shared__ float hl[64];
  __shared__ float ol[10];
  __shared__ float red[2];
  int gid = blockIdx.x, t = threadIdx.x;
  if (t == 0) {
    se = lower_bound_dev(batching, NN, gid);
    ee = lower_bound_dev(batching, NN, gid + 1);
  }
  __syncthreads();
  float acc = 0.f;
  for (int n = se; n < ee; ++n) acc += x[(size_t)n * FDIM + t];
  gl[t] = acc;
  __syncthreads();
  if (t < NFC1) {
    float h = bf1[t];
    for (int f = 0; f < 128; ++f) h += gl[f] * Wf1[f * NFC1 + t];
    hl[t] = h;
  }
  __syncthreads();
  if (t < NFC2) {
    float o = bf2[t];
    for (int i = 0; i < NFC1; ++i) o += hl[i] * Wf2[i * NFC2 + t];
    ol[t] = o;
  }
  __syncthreads();
  if (t == 0) {
    float m = ol[0];
    for (int i = 1; i < NFC2; ++i) m = fmaxf(m, ol[i]);
    float s = 0.f;
    for (int i = 0; i < NFC2; ++i) s += expf(ol[i] - m);
    red[0] = m;
    red[1] = s;
  }
  __syncthreads();
  if (t < NFC2) out[(size_t)gid * NFC2 + t] = expf(ol[t] - red[0]) / red[1];
}

extern "C" void kernel_launch(void* const* d_in, const int* in_sizes, int n_in,
                              void* d_out, int out_size, void* d_ws, size_t ws_size,
                              hipStream_t stream) {
  const float* node_attr = (const float*)d_in[0];
  const float* Wc = (const float*)d_in[1];   // [3][128][128]
  const float* bc = (const float*)d_in[2];   // [3][128]
  const float* Wf1 = (const float*)d_in[3];  // [128][64]
  const float* bf1 = (const float*)d_in[4];
  const float* Wf2 = (const float*)d_in[5];  // [64][10]
  const float* bf2 = (const float*)d_in[6];
  const int* src = (const int*)d_in[7];
  const int* dst = (const int*)d_in[8];
  const int* batching = (const int*)d_in[9];
  float* out = (float*)d_out;

  char* wsp = (char*)d_ws;
  size_t off = 0;
  auto alloc = [&](size_t bytes) -> void* {
    void* p = wsp + off;
    off += (bytes + 255) & ~(size_t)255;
    return p;
  };
  int* row_off = (int*)alloc((size_t)(NN + 1) * sizeof(int));
  int* gcursor = (int*)alloc(NBUCK * sizeof(int));
  int* esrc = (int*)alloc((size_t)NE * sizeof(int));
  float* bufA = (float*)alloc((size_t)NN * FDIM * sizeof(float));
  float* bufB = (float*)alloc((size_t)NN * FDIM * sizeof(float));
  // staging (16.1 MB) aliases bufB: staging is dead before layer-2 writes bufB
  int* staging = (int*)bufB;

  // CSR build via 2-level counting sort
  hipMemsetAsync(gcursor, 0, NBUCK * sizeof(int), stream);
  bin_kernel<<<(NE + 256 * EPB - 1) / (256 * EPB), 256, 0, stream>>>(src, dst, gcursor, staging);
  build_kernel<<<NBUCK, 256, 0, stream>>>(staging, gcursor, row_off, esrc);

  // fused conv layers: gather -> LDS -> GEMM -> relu -> store
  conv_fused<<<(NN + 63) / 64, 512, 0, stream>>>((const float4*)node_attr, row_off, esrc,
                                                 Wc, bc, bufA);
  conv_fused<<<(NN + 63) / 64, 512, 0, stream>>>((const float4*)bufA, row_off, esrc,
                                                 Wc + 16384, bc + 128, bufB);
  conv_fused<<<(NN + 63) / 64, 512, 0, stream>>>((const float4*)bufB, row_off, esrc,
                                                 Wc + 32768, bc + 256, bufA);

  // fused pool + head
  pool_head<<<NG, 128, 0, stream>>>(bufA, batching, Wf1, bf1, Wf2, bf2, out);
}